// Round 1
// baseline (474.845 us; speedup 1.0000x reference)
//
#include <hip/hip_runtime.h>
#include <stdint.h>

// GaussianTrans fused: out[b,r,c,d] = sum_h sig(disX[c,h]+attX[b,r,c,h]) * V[b,r,h,d]
//                                   + sum_w sig(disY[r,w]+attY[b,c,r,w]) * V[b,w,c,d]
// B=16, H=W=64, D=512. fp32 I/O; bf16 MFMA, fp32 accum.
// R4: single fused output-stationary kernel. Kills the Y-pass out RMW (268MB) and the
// second V read (134MB): prep kernel writes sigmoid(dis+att) as bf16 to d_ws once,
// fused kernel stages V[b,:,:,d16] twice from L2 (X-layout then Y-layout), parks the
// X-partial in fp16 LDS, and writes out exactly once (coalesced f32x4).
// Traffic ~336MB vs ~660MB. Grid XCD-swizzled so each b's A' (1MB) stays in one L2.

typedef __attribute__((ext_vector_type(8))) __bf16 bf16x8;
typedef __attribute__((ext_vector_type(8))) short short8;
typedef __attribute__((ext_vector_type(4))) float f32x4;
typedef __attribute__((ext_vector_type(4))) unsigned int uint4v;
typedef __attribute__((ext_vector_type(4))) unsigned short u16x4;

union U8 { short8 s; bf16x8 b; unsigned short u[8]; uint4v q; };

__device__ __forceinline__ unsigned short f2bf(float f) {
    union { float f; unsigned int i; } v; v.f = f;
    return (unsigned short)((v.i + 0x7fffu + ((v.i >> 16) & 1u)) >> 16);  // RNE
}
__device__ __forceinline__ float fsigmoid(float x) {
    float e = __builtin_amdgcn_exp2f(-1.44269504f * x);   // exp(-x)
    return __builtin_amdgcn_rcpf(1.0f + e);
}
__device__ __forceinline__ unsigned short f2h(float f) {
    union { _Float16 h; unsigned short u; } v; v.h = (_Float16)f; return v.u;
}
__device__ __forceinline__ float h2f(unsigned short u) {
    union { _Float16 h; unsigned short us; } v; v.us = u; return (float)v.h;
}

// ---------------- LDS address maps (bank-uniform, 16B-quantized) ----------------
// S_X[r(32)][d(16)][h(64)] bf16, 64KB. XOR h-group with d&7: ds_read_b128 of a
// B-frag (lane: d=l15, h-run=8) hits all 8 16B-columns uniformly (8 lanes each).
__device__ __forceinline__ int sx_addr(int r, int d, int h) {
    return r * 1024 + d * 64 + (h & 7) + ((((h >> 3) ^ (d & 7))) << 3);
}
// S_Y[c(64)][d(16)][w(32 local)] bf16, 64KB. XOR w-group with (d&3, c&1).
__device__ __forceinline__ int sy_addr(int c, int d, int w) {
    return c * 512 + d * 32 + (w & 7) + (((w >> 3) ^ (d & 3) ^ ((c & 1) << 1)) << 3);
}
// olds[d(16)][r(32)][c(64)] fp16, 64KB: X-partial parking. c XOR-swizzled by (r&3, d>>2)
// so both the b64 dump (lane d=l15) and the scalar epilogue reads spread banks.
__device__ __forceinline__ int ol_addr(int d, int r, int c) {
    return d * 2048 + r * 64 + (c ^ ((r & 3) << 2) ^ ((d >> 2) << 4));
}

// ---------------- prep: A' = bf16(sigmoid(dis + att)) ----------------
// attX[b,r,c,h]: dis=-(shift*(h-c)^2+bias); attY[b,c,r,w]: dis=-(shift*(w-r)^2+bias).
// Same formula on the last two index dims for both tensors.
__device__ __forceinline__ void sig16(const float* __restrict__ in,
                                      unsigned short* __restrict__ outp,
                                      int l0, int sec, float shift, float bias) {
    f32x4 v[4];
#pragma unroll
    for (int j = 0; j < 4; ++j) v[j] = *(const f32x4*)(in + 4 * j);
    U8 r0, r1;
#pragma unroll
    for (int e = 0; e < 16; ++e) {
        float dd = (float)(l0 + e - sec);
        float dis = -(shift * dd * dd + bias);
        unsigned short us = f2bf(fsigmoid(dis + v[e >> 2][e & 3]));
        if (e < 8) r0.u[e] = us; else r1.u[e - 8] = us;
    }
    *(uint4v*)(outp) = r0.q;
    *(uint4v*)(outp + 8) = r1.q;
}

__global__ __launch_bounds__(256)
void prep_sig(const float* __restrict__ attX, const float* __restrict__ attY,
              unsigned short* __restrict__ aX, unsigned short* __restrict__ aY,
              const float* __restrict__ shiftp, const float* __restrict__ biasp) {
    const float shift = shiftp[0];
    const float bias  = biasp[0];
    const size_t base = ((size_t)blockIdx.x * 256 + threadIdx.x) * 16;
    const int sec = (int)((base >> 6) & 63);
    const int l0  = (int)(base & 63);
    sig16(attX + base, aX + base, l0, sec, shift, bias);
    sig16(attY + base, aY + base, l0, sec, shift, bias);
}

// ---------------- fused GEMM ----------------
// Block: (b, dg in 0..15 [32 d-floats], rh in 0..1 [32 r-rows]); 512 thr = 8 waves
// (cg 0..3 x rg 0..1). Wave owns out[b, rbase+rg*16+0..15, cg*16+0..15, d16].
// Per dc (two d16 chunks):
//   stage S_X = V[b, r-half, :, d16]  -> X GEMMs (A'X global frags from L2, m=c)
//   dump accX -> olds (fp16, intra-wave region, no barrier needed)
//   2x: stage S_Y = V[b, w-half, :, d16] -> Y GEMMs transposed (m=d, n=r; A=slab, B=A'Y)
//   epilogue: accY + olds -> out, one f32x4 (d-run) per lane per c.
__global__ __launch_bounds__(512, 2)
void gauss_fused(const unsigned short* __restrict__ aX,
                 const unsigned short* __restrict__ aY,
                 const float* __restrict__ V,
                 float* __restrict__ out) {
    __shared__ unsigned short slab[32768];  // 64KB: S_X or S_Y (phase-exclusive)
    __shared__ unsigned short olds[32768];  // 64KB: fp16 X-partial

    // XCD swizzle: p = (b&7) + 8*((b>>3)*32 + dg*2 + rh): all 32 blocks of a given b
    // land on one XCD (A'[b]=1MB L2-resident); rh-twins adjacent for V slab sharing.
    const int p   = blockIdx.x;
    const int xcd = p & 7;
    const int k   = p >> 3;
    const int b   = ((k >> 5) << 3) | xcd;
    const int dg  = (k & 31) >> 1;
    const int rh  = k & 1;
    const int rbase = rh * 32;

    const int t    = threadIdx.x;
    const int lane = t & 63;
    const int wid  = t >> 6;
    const int cg   = wid & 3;
    const int rg   = wid >> 2;
    const int l15  = lane & 15;
    const int quad = lane >> 4;

    const size_t vbase = (size_t)b * 2097152;  // b*64*64*512

#pragma unroll
    for (int dc = 0; dc < 2; ++dc) {
        const int dstart = dg * 32 + dc * 16;

        __syncthreads();  // slab free (prev iter's Y reads done)

        // ---- stage S_X: V[b, rbase+r, h, d16] -> [r][d][h] bf16 ----
        {
            const int r  = t >> 4;   // 0..31
            const int hq = t & 15;   // h = 4*hq + i
            const float* vp = V + vbase + (size_t)(rbase + r) * 32768
                            + (size_t)(4 * hq) * 512 + dstart;
            f32x4 vv[4][4];
#pragma unroll
            for (int i = 0; i < 4; ++i)
#pragma unroll
                for (int j = 0; j < 4; ++j)
                    vv[i][j] = *(const f32x4*)(vp + i * 512 + 4 * j);
#pragma unroll
            for (int d = 0; d < 16; ++d) {
                u16x4 pk;
#pragma unroll
                for (int i = 0; i < 4; ++i) pk[i] = f2bf(vv[i][d >> 2][d & 3]);
                *(u16x4*)&slab[sx_addr(r, d, 4 * hq)] = pk;
            }
        }
        __syncthreads();

        // ---- X GEMMs: per r, D_r[c][d16] += A'X[b,r,c,h] * S_X[r][d][h] ----
        f32x4 accX[16];
#pragma unroll
        for (int rr = 0; rr < 16; ++rr) accX[rr] = (f32x4)0.0f;
#pragma unroll
        for (int ks = 0; ks < 2; ++ks) {
            bf16x8 af[16];
#pragma unroll
            for (int rr = 0; rr < 16; ++rr) {
                const unsigned short* ap = aX
                    + ((size_t)((b * 64 + rbase + rg * 16 + rr) * 64 + (cg * 16 + l15))) * 64
                    + ks * 32 + quad * 8;
                U8 u; u.q = *(const uint4v*)ap; af[rr] = u.b;
            }
#pragma unroll
            for (int rr = 0; rr < 16; ++rr) {
                U8 bu;
                bu.q = *(const uint4v*)&slab[sx_addr(rg * 16 + rr, l15, ks * 32 + quad * 8)];
                accX[rr] = __builtin_amdgcn_mfma_f32_16x16x32_bf16(af[rr], bu.b, accX[rr], 0, 0, 0);
            }
        }

        // ---- park X partial as fp16 (own-wave region of olds; no barrier needed) ----
#pragma unroll
        for (int rr = 0; rr < 16; ++rr) {
            u16x4 pk;
#pragma unroll
            for (int reg = 0; reg < 4; ++reg) pk[reg] = f2h(accX[rr][reg]);
            *(u16x4*)&olds[ol_addr(l15, rg * 16 + rr, cg * 16 + quad * 4)] = pk;
        }

        // ---- Y GEMMs (transposed: m=d, n=r), K split in two w-halves ----
        f32x4 accY[16];
#pragma unroll
        for (int cc = 0; cc < 16; ++cc) accY[cc] = (f32x4)0.0f;
#pragma unroll
        for (int half = 0; half < 2; ++half) {
            __syncthreads();  // slab reads of previous phase done
            {   // stage S_Y: V[b, half*32+w, c, d16] -> [c][d][w] bf16
                const int c  = t >> 3;  // 0..63
                const int wq = t & 7;   // w local = 4*wq + i
                const float* vp = V + vbase + (size_t)(half * 32 + 4 * wq) * 32768
                                + (size_t)c * 512 + dstart;
                f32x4 vv[4][4];
#pragma unroll
                for (int i = 0; i < 4; ++i)
#pragma unroll
                    for (int j = 0; j < 4; ++j)
                        vv[i][j] = *(const f32x4*)(vp + (size_t)i * 32768 + 4 * j);
#pragma unroll
                for (int d = 0; d < 16; ++d) {
                    u16x4 pk;
#pragma unroll
                    for (int i = 0; i < 4; ++i) pk[i] = f2bf(vv[i][d >> 2][d & 3]);
                    *(u16x4*)&slab[sy_addr(c, d, 4 * wq)] = pk;
                }
            }
            __syncthreads();
            bf16x8 bg[16];
#pragma unroll
            for (int cc = 0; cc < 16; ++cc) {
                const unsigned short* ap = aY
                    + ((size_t)((b * 64 + cg * 16 + cc) * 64 + (rbase + rg * 16 + l15))) * 64
                    + half * 32 + quad * 8;
                U8 u; u.q = *(const uint4v*)ap; bg[cc] = u.b;
            }
#pragma unroll
            for (int cc = 0; cc < 16; ++cc) {
                U8 au;
                au.q = *(const uint4v*)&slab[sy_addr(cg * 16 + cc, l15, quad * 8)];
                accY[cc] = __builtin_amdgcn_mfma_f32_16x16x32_bf16(au.b, bg[cc], accY[cc], 0, 0, 0);
            }
        }

        // ---- epilogue: out = accY + fp16(X-partial); lane owns d-run of 4 ----
        {
            float* ob = out + vbase + (size_t)(rbase + rg * 16 + l15) * 32768 + dstart + quad * 4;
#pragma unroll
            for (int cc = 0; cc < 16; ++cc) {
                f32x4 res;
#pragma unroll
                for (int reg = 0; reg < 4; ++reg)
                    res[reg] = accY[cc][reg]
                             + h2f(olds[ol_addr(quad * 4 + reg, rg * 16 + l15, cg * 16 + cc)]);
                *(f32x4*)(ob + (size_t)(cg * 16 + cc) * 512) = res;
            }
        }
    }
}

// ---------------- fallback (ws too small): previous two-pass R3 kernel ----------------
template <int S_I, int S_K, bool ACCUM>
__global__ __launch_bounds__(256)
void gauss_gemm(const float* __restrict__ att,
                const float* __restrict__ V,
                float* __restrict__ out,
                const float* __restrict__ shiftp,
                const float* __restrict__ biasp) {
    __shared__ unsigned short S[4096];
    __shared__ unsigned short VT[128 * 66];

    const int bid    = blockIdx.x;
    const int dq     = bid & 3;
    const int i      = (bid >> 2) & 63;
    const int b      = bid >> 8;
    const int t      = threadIdx.x;
    const int dstart = dq * 128;

    const float shift = shiftp[0];
    const float bias  = biasp[0];
    const size_t base = (size_t)b * 2097152 + (size_t)i * S_I;

    const float* ab = att + (size_t)(b * 64 + i) * 4096;
#pragma unroll
    for (int chunk = 0; chunk < 2; ++chunk) {
        int flat = t + chunk * 256;
        int q = flat >> 6, m = flat & 63;
        const float* ap = ab + m * 64 + q * 8;
        f32x4 av0 = *(const f32x4*)(ap);
        f32x4 av1 = *(const f32x4*)(ap + 4);
        U8 res;
#pragma unroll
        for (int j = 0; j < 8; ++j) {
            float a    = (j < 4) ? av0[j & 3] : av1[j & 3];
            float diff = (float)(q * 8 + j - m);
            float dis  = -(shift * diff * diff + bias);
            res.u[j]   = f2bf(fsigmoid(dis + a));
        }
        *(short8*)(&S[flat * 8]) = res.s;
    }
    {
        const float* vb = V + base + dstart;
        const int d4 = t & 31;
        const int h0 = t >> 5;
#pragma unroll
        for (int it = 0; it < 8; ++it) {
            const int h = h0 + it * 8;
            f32x4 v = *(const f32x4*)(vb + (size_t)h * S_K + 4 * d4);
#pragma unroll
            for (int u = 0; u < 4; ++u)
                VT[(4 * d4 + u) * 66 + h] = f2bf(v[u]);
        }
    }
    __syncthreads();

    const int lane = t & 63, wid = t >> 6;
    const int l15 = lane & 15, quad = lane >> 4;

    f32x4 acc[4][2];
#pragma unroll
    for (int mt = 0; mt < 4; ++mt)
#pragma unroll
        for (int nt = 0; nt < 2; ++nt) acc[mt][nt] = (f32x4)0.0f;

#pragma unroll
    for (int ks = 0; ks < 2; ++ks) {
        bf16x8 af[4];
#pragma unroll
        for (int mt = 0; mt < 4; ++mt) {
            U8 a;
            a.s = *(const short8*)(&S[((ks * 4 + quad) * 64 + mt * 16 + l15) * 8]);
            af[mt] = a.b;
        }
        const int h = ks * 32 + quad * 8;
#pragma unroll
        for (int nt = 0; nt < 2; ++nt) {
            const int dloc = wid * 32 + nt * 16 + l15;
            const unsigned short* vp = &VT[dloc * 66 + h];
            U8 bvec;
            uint4v qv;
#pragma unroll
            for (int u = 0; u < 4; ++u) qv[u] = *(const unsigned int*)(vp + 2 * u);
            bvec.q = qv;
#pragma unroll
            for (int mt = 0; mt < 4; ++mt)
                acc[mt][nt] = __builtin_amdgcn_mfma_f32_16x16x32_bf16(
                    af[mt], bvec.b, acc[mt][nt], 0, 0, 0);
        }
    }

    float* ob = out + base + dstart;
#pragma unroll
    for (int mt = 0; mt < 4; ++mt)
#pragma unroll
        for (int nt = 0; nt < 2; ++nt)
#pragma unroll
            for (int reg = 0; reg < 4; ++reg) {
                int m = mt * 16 + quad * 4 + reg;
                int d = wid * 32 + nt * 16 + l15;
                size_t off = (size_t)m * S_K + d;
                float v = acc[mt][nt][reg];
                if (ACCUM) v += ob[off];
                ob[off] = v;
            }
}

extern "C" void kernel_launch(void* const* d_in, const int* in_sizes, int n_in,
                              void* d_out, int out_size, void* d_ws, size_t ws_size,
                              hipStream_t stream) {
    // inputs (fp32): 0=x (UNUSED), 1=attentionXFull, 2=attentionYFull,
    //                3=valueFull, 4=shift, 5=bias
    const float* attX = (const float*)d_in[1];
    const float* attY = (const float*)d_in[2];
    const float* V    = (const float*)d_in[3];
    const float* shp  = (const float*)d_in[4];
    const float* bip  = (const float*)d_in[5];
    float* out = (float*)d_out;

    const size_t ATT_ELEMS = 16ull * 64 * 64 * 64;  // 4,194,304 per tensor
    if (ws_size >= ATT_ELEMS * 2 * sizeof(unsigned short)) {
        unsigned short* aXw = (unsigned short*)d_ws;
        unsigned short* aYw = aXw + ATT_ELEMS;
        prep_sig<<<dim3(1024), dim3(256), 0, stream>>>(attX, attY, aXw, aYw, shp, bip);
        gauss_fused<<<dim3(512), dim3(512), 0, stream>>>(aXw, aYw, V, out);
    } else {
        dim3 blk(256);
        dim3 grid(16 * 64 * 4);
        gauss_gemm<32768, 512, false><<<grid, blk, 0, stream>>>(attX, V, out, shp, bip);
        gauss_gemm<512, 32768, true><<<grid, blk, 0, stream>>>(attY, V, out, shp, bip);
    }
}